// Round 4
// baseline (241.410 us; speedup 1.0000x reference)
//
#include <hip/hip_runtime.h>
#include <hip/hip_bf16.h>
#include <hip/hip_cooperative_groups.h>

namespace cg = cooperative_groups;

// ---------------------------------------------------------------------------
// InferCellV2 R10: one cooperative kernel, DAG-fused passes, register partials.
// R6/R8/R9 triangulation: structure is LDS-read-byte bound (147KB per 64x64
// wave-tile edge-pass through the 85B/cyc LDS pipe = 7.1MB/CU over 6 edge
// passes ~= 35us floor) + 6 serial A-staging bursts (~21us). R9 (A from L2)
// regressed: latency-bound at 6 waves/CU. Fix the ARITHMETIC, not the
// schedule: r0 feeds 3 edges, r1 feeds 2 -> read each A-fragment once for
// multiple edges (interleaved per (tap,q): Af feeds 32 MFMA -> LDS 144cyc vs
// MFMA 155cyc, balanced) and stage each source once. Requires edge partials
// to persist across sources: single cooperative kernel, grid 256 = 1
// block/CU (co-residency guaranteed), grid.sync() between passes, partial
// accs (node2, node3) live in VGPRs across syncs (peak 128 acc regs; node1's
// acc dies before node3's is born -> never 3 live).
//   P1: stage A(r0); edges {0->aT(node1), 1->aX(node2)} interleaved;
//       write node1; edge {3->aY(node3)}.  sync.
//   P2: stage A(r1); edges {2->aX, 4->aY} interleaved; write node2.  sync.
//   P3: stage A(r2); edge {5->aY}; write out fp32.
// B staged per-tap into 4 ping-pong 8KB slots (32KB): tap t+1 issued before
// computing tap t (one gld_lds chunk/thread from L2-hot 442KB wt), barrier
// per tap drains it. LDS = 18-row A (78336) + 32768 = 111104B, 8 waves/CU.
// Layouts/tile math unchanged from R6/R8 (verified, conflict-free):
//   activations: zero-padded NHWC bf16 [B][34][34][64], chunk cb of pixel p
//     at p*128 + ((cb^(p&7))*16); weights wt[l][tap][o][i], chunk i>>3 of
//     row o at slot (i>>3)^(o&7). Wave tile 64px x 64oc, 4x4 MFMA 16x16x32.
// ---------------------------------------------------------------------------

typedef __bf16 bf16x8 __attribute__((ext_vector_type(8)));
typedef float floatx4 __attribute__((ext_vector_type(4)));
typedef unsigned int uint32;

#define PADW 34
#define PIMG (PADW * PADW)
#define ROWB (PADW * 64 * 2)        // 4352 B per padded NHWC row
#define A_LDS (18 * ROWB)           // 78336 (16 out rows + 2 halo)
#define A_TAIL 288                  // 4896 chunks = 9*512 + 288
#define TAPB (64 * 64 * 2)          // 8192 B per weight tap
#define SMEM_BYTES (A_LDS + 4 * TAPB)  // 111104 -> 1 block/CU

__device__ __forceinline__ void gld16(const char* g, char* l) {
    __builtin_amdgcn_global_load_lds(
        (const __attribute__((address_space(1))) uint32*)g,
        (__attribute__((address_space(3))) uint32*)l, 16, 0, 0);
}

// ---------------- fused pre-pass: prep_weights + zero_halo + relu_pad -------
__global__ __launch_bounds__(256) void pre_kernel(
    const float* __restrict__ in, const float* __restrict__ a1,
    const float* __restrict__ a2, const float* __restrict__ W,
    __hip_bfloat16* __restrict__ wt, __hip_bfloat16* __restrict__ r0,
    __hip_bfloat16* __restrict__ r1, __hip_bfloat16* __restrict__ r2) {
    __shared__ float tile[32][65];
    int blk = blockIdx.x;
    int tid = threadIdx.x;

    if (blk < 864) {                 // ---- weights: fold scale + swizzle
        int idx = blk * 256 + tid;   // 6*9*64*64 = 221184 exact
        int i = idx & 63;
        int o = (idx >> 6) & 63;
        int rest = idx >> 12;
        int t = rest % 9;
        int l = rest / 9;
        int ji = i >> 3, jo = o >> 3;
        float ain = 0.f, aout = 0.f;
#pragma unroll
        for (int j = 0; j < 8; ++j) {
            ain  += (j >= ji) ? a1[j] : 0.f;
            aout += (j >= jo) ? a2[j] : 0.f;
        }
        float v = W[(size_t)((l * 64 + o) * 64 + i) * 9 + t] * ain * aout;
        size_t e = (size_t)(l * 9 + t) * 4096 + o * 64 +
                   ((((i >> 3) ^ (o & 7)) << 3) + (i & 7));
        wt[e] = __float2bfloat16(v);
    } else if (blk < 992) {          // ---- zero halo ring, image b
        int b = blk - 864;
        __hip_bfloat16* bufs[3] = {r0, r1, r2};
#pragma unroll
        for (int f = 0; f < 3; ++f) {
            uint32* buf = (uint32*)(bufs[f] + (size_t)b * PIMG * 64);
            for (int idx = tid; idx < 132 * 32; idx += 256) {
                int slot = idx >> 5, u = idx & 31;
                int yy, xx;
                if (slot < 34)      { yy = 0;  xx = slot; }
                else if (slot < 68) { yy = 33; xx = slot - 34; }
                else { int s2 = slot - 68; yy = 1 + (s2 >> 1); xx = (s2 & 1) * 33; }
                buf[(size_t)(yy * PADW + xx) * 32 + u] = 0u;
            }
        }
    } else {                         // ---- relu(x) -> padded swizzled NHWC
        int rb = blk - 992;
        int b = rb >> 5, y = rb & 31;
        int x = tid & 31, c0 = tid >> 5;
        const float* ip = in + ((size_t)b * 64 * 32 + y) * 32 + x;
#pragma unroll
        for (int cc = 0; cc < 8; ++cc) {
            int c = cc * 8 + c0;
            tile[x][c] = fmaxf(ip[(size_t)c * 1024], 0.f);
        }
        __syncthreads();
        // one 16B chunk store per thread: thread = (pixel xq, chunk j);
        // chunk j of pixel p lives at p*128 + (j^(p&7))*16.
        int j = tid & 7, xq = tid >> 3;
        int p = (b * PADW + y + 1) * PADW + 1 + xq;
        alignas(16) __hip_bfloat16 hv[8];
#pragma unroll
        for (int k = 0; k < 8; ++k)
            hv[k] = __float2bfloat16(tile[xq][j * 8 + k]);
        *(uint4*)((char*)r0 + (size_t)p * 128 + ((j ^ (p & 7)) << 4)) =
            *(const uint4*)hv;
    }
}

// ---- one weight tap (8192B = 512 chunks = 1 chunk/thread) -> slot ---------
__device__ __forceinline__ void stage_tap(const char* wt, int l, int t,
                                          int slot, char* smemB, int tid,
                                          int wv) {
    const char* g = wt + ((size_t)l * 9 + t) * TAPB;
    gld16(g + (size_t)tid * 16, smemB + slot * TAPB + wv * 64 * 16);
}

// ---- 9-tap edge phase: NE edges share each A-fragment ---------------------
// Per tap: issue tap t+1's B staging (ping-pong slots), compute from slot
// (t&1)*2, barrier (drains vmcnt -> t+1 resident; guards slot reuse).
template <int NE>
__device__ __forceinline__ void run_phase(
    char* smem, char* smemB, const char* wt, int lA, int lB, int wv,
    int quad, int l15, int tid, int Rb,
    floatx4 (&accA)[4][4], floatx4 (&accB)[4][4]) {
    stage_tap(wt, lA, 0, 0, smemB, tid, wv);
    if (NE == 2) stage_tap(wt, lB, 0, 1, smemB, tid, wv);
    __syncthreads();                 // A (pass prologue) + B(t=0) resident
#pragma unroll 1
    for (int t = 0; t < 9; ++t) {
        if (t < 8) {
            int ns = ((t + 1) & 1) * 2;
            stage_tap(wt, lA, t + 1, ns, smemB, tid, wv);
            if (NE == 2) stage_tap(wt, lB, t + 1, ns + 1, smemB, tid, wv);
        }
        __builtin_amdgcn_sched_barrier(0);   // keep staging issue up top
        int ky = (t >= 3) + (t >= 6);        // t wave-uniform -> SALU
        int kx = t - 3 * ky;
        int sb = (t & 1) * 2;
#pragma unroll
        for (int q = 0; q < 2; ++q) {
            bf16x8 Af[4];
#pragma unroll
            for (int m = 0; m < 4; ++m) {
                int arow = 2 * wv + (m >> 1) + ky;      // LDS row 0..17
                int apx  = ((m & 1) << 4) + l15 + kx;   // 0..33
                int R = Rb + arow;                       // global padded row
                int slot = ((q << 2) + quad) ^ ((2 * R + apx) & 7);
                Af[m] = *(const bf16x8*)(smem + arow * ROWB + apx * 128 +
                                         slot * 16);
            }
            {
                bf16x8 Bf[4];
#pragma unroll
                for (int n = 0; n < 4; ++n) {
                    int o = (n << 4) + l15;
                    int slot = ((q << 2) + quad) ^ (l15 & 7);
                    Bf[n] = *(const bf16x8*)(smemB + sb * TAPB + o * 128 +
                                             slot * 16);
                }
                __builtin_amdgcn_s_setprio(1);
#pragma unroll
                for (int m = 0; m < 4; ++m)
#pragma unroll
                    for (int n = 0; n < 4; ++n)
                        accA[m][n] = __builtin_amdgcn_mfma_f32_16x16x32_bf16(
                            Af[m], Bf[n], accA[m][n], 0, 0, 0);
                __builtin_amdgcn_s_setprio(0);
            }
            if (NE == 2) {
                bf16x8 Bf[4];
#pragma unroll
                for (int n = 0; n < 4; ++n) {
                    int o = (n << 4) + l15;
                    int slot = ((q << 2) + quad) ^ (l15 & 7);
                    Bf[n] = *(const bf16x8*)(smemB + (sb + 1) * TAPB +
                                             o * 128 + slot * 16);
                }
                __builtin_amdgcn_s_setprio(1);
#pragma unroll
                for (int m = 0; m < 4; ++m)
#pragma unroll
                    for (int n = 0; n < 4; ++n)
                        accB[m][n] = __builtin_amdgcn_mfma_f32_16x16x32_bf16(
                            Af[m], Bf[n], accB[m][n], 0, 0, 0);
                __builtin_amdgcn_s_setprio(0);
            }
        }
        __syncthreads();             // t+1 B resident; slot reuse safe
    }
}

// ---- epilogues (tile math verified in R6) ---------------------------------
__device__ __forceinline__ void epi_bf16(floatx4 (&acc)[4][4],
                                         __hip_bfloat16* dst, int b, int y0,
                                         int wv, int quad, int l15) {
#pragma unroll
    for (int m = 0; m < 4; ++m) {
        int row = y0 + 2 * wv + (m >> 1);
#pragma unroll
        for (int n = 0; n < 4; ++n) {
            int o = (n << 4) + l15;
#pragma unroll
            for (int r = 0; r < 4; ++r) {
                int x = ((m & 1) << 4) + (quad << 2) + r;
                int p = (b * PADW + row + 1) * PADW + x + 1;
                float v = fmaxf(acc[m][n][r], 0.f);
                size_t e = (size_t)p * 64 +
                           ((((o >> 3) ^ (p & 7)) << 3) + (o & 7));
                dst[e] = __float2bfloat16(v);
            }
        }
    }
}

__device__ __forceinline__ void epi_f32(floatx4 (&acc)[4][4], float* out,
                                        int b, int y0, int wv, int quad,
                                        int l15) {
#pragma unroll
    for (int m = 0; m < 4; ++m) {
        int row = y0 + 2 * wv + (m >> 1);
#pragma unroll
        for (int n = 0; n < 4; ++n) {
            int o = (n << 4) + l15;
            *(floatx4*)(out + (((size_t)b * 64 + o) * 32 + row) * 32 +
                        ((m & 1) << 4) + (quad << 2)) = acc[m][n];
        }
    }
}

#define ZERO4(A_)                                                        \
    _Pragma("unroll") for (int m_ = 0; m_ < 4; ++m_)                     \
    _Pragma("unroll") for (int n_ = 0; n_ < 4; ++n_)                     \
        A_[m_][n_] = (floatx4){0.f, 0.f, 0.f, 0.f};

// ---------------- the cell kernel (cooperative) ----------------------------
// Block: image b = blk>>1, strip y0 = (blk&1)*16. Wave wv(0..7): rows
// y0+2wv, +1. Grid 256 = 1 block/CU.
__global__ __launch_bounds__(512, 2) void cell_kernel(
    const __hip_bfloat16* __restrict__ r0, __hip_bfloat16* __restrict__ r1,
    __hip_bfloat16* __restrict__ r2, const __hip_bfloat16* __restrict__ wtb,
    float* __restrict__ out) {
    extern __shared__ char smem[];               // A 78336 + B 32768
    char* smemB = smem + A_LDS;
    int tid = threadIdx.x;
    int wv = tid >> 6, lane = tid & 63;
    int quad = lane >> 4, l15 = lane & 15;
    int blk = blockIdx.x;
    int b = blk >> 1, y0 = (blk & 1) << 4;
    int Rb = b * PADW + y0;
    const char* wt = (const char*)wtb;

    auto stage_A = [&](const __hip_bfloat16* src) {  // 18 rows, linear DMA
        const char* gA = (const char*)src + (size_t)Rb * PADW * 128;
#pragma unroll
        for (int it = 0; it < 10; ++it) {
            int c = it * 512 + tid;
            if (it < 9 || tid < A_TAIL)
                gld16(gA + (size_t)c * 16, smem + (it * 512 + wv * 64) * 16);
        }
    };

    floatx4 aT[4][4], aX[4][4], aY[4][4];

    // ---- Pass 1: source r0 -> edges 0 (node1), 1 (node2p), 3 (node3p)
    ZERO4(aT); ZERO4(aX);
    stage_A(r0);
    run_phase<2>(smem, smemB, wt, 0, 1, wv, quad, l15, tid, Rb, aT, aX);
    epi_bf16(aT, r1, b, y0, wv, quad, l15);      // node1 = relu -> r1
    ZERO4(aY);                                   // aT dead -> aY born
    run_phase<1>(smem, smemB, wt, 3, 3, wv, quad, l15, tid, Rb, aY, aY);
    cg::this_grid().sync();                      // node1 visible everywhere

    // ---- Pass 2: source r1 -> edges 2 (node2), 4 (node3p)
    stage_A(r1);
    run_phase<2>(smem, smemB, wt, 2, 4, wv, quad, l15, tid, Rb, aX, aY);
    epi_bf16(aX, r2, b, y0, wv, quad, l15);      // node2 = relu -> r2
    cg::this_grid().sync();                      // node2 visible everywhere

    // ---- Pass 3: source r2 -> edge 5 (node3)
    stage_A(r2);
    run_phase<1>(smem, smemB, wt, 5, 5, wv, quad, l15, tid, Rb, aY, aY);
    epi_f32(aY, out, b, y0, wv, quad, l15);      // fp32 NCHW, no relu
}

// ---------------------------------------------------------------------------
extern "C" void kernel_launch(void* const* d_in, const int* in_sizes, int n_in,
                              void* d_out, int out_size, void* d_ws,
                              size_t ws_size, hipStream_t stream) {
    const float* inputs  = (const float*)d_in[0];
    const float* alphas1 = (const float*)d_in[1];
    const float* alphas2 = (const float*)d_in[2];
    const float* W       = (const float*)d_in[3];
    char* ws = (char*)d_ws;

    __hip_bfloat16* wt = (__hip_bfloat16*)(ws);                     // 442 KB
    __hip_bfloat16* r0 = (__hip_bfloat16*)(ws + ((size_t)1 << 20)); // 18.9 MB
    __hip_bfloat16* r1 = (__hip_bfloat16*)(ws + ((size_t)20 << 20));
    __hip_bfloat16* r2 = (__hip_bfloat16*)(ws + ((size_t)40 << 20));
    float* out = (float*)d_out;

    // Opt-in to >64KB dynamic LDS (idempotent; harmless under graph capture).
    (void)hipFuncSetAttribute((const void*)cell_kernel,
                              hipFuncAttributeMaxDynamicSharedMemorySize,
                              SMEM_BYTES);

    pre_kernel<<<864 + 128 + 4096, 256, 0, stream>>>(inputs, alphas1, alphas2,
                                                     W, wt, r0, r1, r2);

    void* kargs[] = {(void*)&r0, (void*)&r1, (void*)&r2, (void*)&wt,
                     (void*)&out};
    (void)hipLaunchCooperativeKernel(reinterpret_cast<void*>(cell_kernel),
                                     dim3(256), dim3(512), kargs,
                                     (unsigned)SMEM_BYTES, stream);
}

// Round 5
// 169.891 us; speedup vs baseline: 1.4210x; 1.4210x over previous
//
#include <hip/hip_runtime.h>
#include <hip/hip_bf16.h>

// ---------------------------------------------------------------------------
// InferCellV2 R11: R6 champion structure + three bounded fixes.
// R7/R10 unified post-mortem: 512-thr kernels with __launch_bounds__(512,2)
// get a ~128-VGPR budget from the allocator -> any >128-reg plan spills
// (R7: 100+spill @212 demand, R10: 128+spill @230 demand, both with
// FETCH/WRITE ballooned by scratch). 256-thr kernels at the same arg
// allocate 128 cleanly (R8/R9). With 152KB LDS we are 1 block/CU anyway, so
// (512,1) raises the cap for free. R10's cooperative launch also added
// ~85us of graph overhead -> back to 3 plain kernels.
// Changes vs R6:
//  1. __launch_bounds__(512,1).
//  2. A-only register prefetch at source switches (pfA[10] = 40 VGPRs;
//     B stays global_load_lds from the L2-hot 442KB wt). Kills the 3
//     serial A-restage HBM bursts. Commit = 10 ds_write_b128 after the
//     read-done barrier. sched_barrier(0) pins the issue point.
//  3. OC-permuted weight storage: wt stores true-oc o at storage col
//     o_s=(o&3)*16+(o>>2), so acc col c=n*16+l15 holds true oc l15*4+n.
//     -> each lane's 4 n-accs are contiguous true channels: bf16 node
//     epilogue becomes 16x 8B aligned stores/thread (was 64x 2B scatter);
//     activations remain true-channel-ordered (no consumer changes);
//     fp32 epilogue addresses oc = l15*4+n.
// Layouts otherwise unchanged (verified conflict-free R3/R6):
//   activations: zero-padded NHWC bf16 [B][34][34][64], chunk cb of pixel p
//     at p*128 + ((cb^(p&7))*16); weights wt[l][tap][o_s][i], chunk i>>3 of
//     row o_s at slot (i>>3)^(o_s&7). Staging = linear 16B chunks.
// Block 512 thr / 8 waves / 16 out rows; grid 256 = 1 block/CU.
// Wave tile 64px x 64oc = 4x4 MFMA 16x16x32, 64 acc VGPRs.
// ---------------------------------------------------------------------------

typedef __bf16 bf16x8 __attribute__((ext_vector_type(8)));
typedef float floatx4 __attribute__((ext_vector_type(4)));
typedef unsigned int uint32;

#define PADW 34
#define PIMG (PADW * PADW)
#define ROWB (PADW * 64 * 2)        // 4352 B per padded NHWC row
#define A_LDS (18 * ROWB)           // 78336 (16 out rows + 2 halo)
#define A_CHUNKS (A_LDS / 16)       // 4896 = 9*512 + 288
#define A_TAIL (A_CHUNKS - 9 * 512) // 288
#define TAPB (64 * 64 * 2)          // 8192 B per weight tap
#define B_LDS (9 * TAPB)            // 73728
#define SMEM_BYTES (A_LDS + B_LDS)  // 152064 -> 1 block/CU

__device__ __forceinline__ void gld16(const char* g, char* l) {
    __builtin_amdgcn_global_load_lds(
        (const __attribute__((address_space(1))) uint32*)g,
        (__attribute__((address_space(3))) uint32*)l, 16, 0, 0);
}

// ---------------- fused pre-pass: prep_weights + zero_halo + relu_pad -------
__global__ __launch_bounds__(256) void pre_kernel(
    const float* __restrict__ in, const float* __restrict__ a1,
    const float* __restrict__ a2, const float* __restrict__ W,
    __hip_bfloat16* __restrict__ wt, __hip_bfloat16* __restrict__ r0,
    __hip_bfloat16* __restrict__ r1, __hip_bfloat16* __restrict__ r2) {
    __shared__ float tile[32][65];
    int blk = blockIdx.x;
    int tid = threadIdx.x;

    if (blk < 864) {                 // ---- weights: fold scale + swizzle
        int idx = blk * 256 + tid;   // 6*9*64*64 = 221184 exact
        int i = idx & 63;
        int o = (idx >> 6) & 63;     // TRUE oc
        int rest = idx >> 12;
        int t = rest % 9;
        int l = rest / 9;
        int ji = i >> 3, jo = o >> 3;
        float ain = 0.f, aout = 0.f;
#pragma unroll
        for (int j = 0; j < 8; ++j) {
            ain  += (j >= ji) ? a1[j] : 0.f;
            aout += (j >= jo) ? a2[j] : 0.f;
        }
        float v = W[(size_t)((l * 64 + o) * 64 + i) * 9 + t] * ain * aout;
        // storage col o_s: acc col c = n*16+l15 then holds true oc l15*4+n
        int os = ((o & 3) << 4) + (o >> 2);
        size_t e = (size_t)(l * 9 + t) * 4096 + os * 64 +
                   ((((i >> 3) ^ (os & 7)) << 3) + (i & 7));
        wt[e] = __float2bfloat16(v);
    } else if (blk < 992) {          // ---- zero halo ring, image b
        int b = blk - 864;
        __hip_bfloat16* bufs[3] = {r0, r1, r2};
#pragma unroll
        for (int f = 0; f < 3; ++f) {
            uint32* buf = (uint32*)(bufs[f] + (size_t)b * PIMG * 64);
            for (int idx = tid; idx < 132 * 32; idx += 256) {
                int slot = idx >> 5, u = idx & 31;
                int yy, xx;
                if (slot < 34)      { yy = 0;  xx = slot; }
                else if (slot < 68) { yy = 33; xx = slot - 34; }
                else { int s2 = slot - 68; yy = 1 + (s2 >> 1); xx = (s2 & 1) * 33; }
                buf[(size_t)(yy * PADW + xx) * 32 + u] = 0u;
            }
        }
    } else {                         // ---- relu(x) -> padded swizzled NHWC
        int rb = blk - 992;
        int b = rb >> 5, y = rb & 31;
        int x = tid & 31, c0 = tid >> 5;
        const float* ip = in + ((size_t)b * 64 * 32 + y) * 32 + x;
#pragma unroll
        for (int cc = 0; cc < 8; ++cc) {
            int c = cc * 8 + c0;
            tile[x][c] = fmaxf(ip[(size_t)c * 1024], 0.f);
        }
        __syncthreads();
        // one 16B chunk store per thread: thread = (pixel xq, chunk j);
        // chunk j of pixel p lives at p*128 + (j^(p&7))*16.
        int j = tid & 7, xq = tid >> 3;
        int p = (b * PADW + y + 1) * PADW + 1 + xq;
        alignas(16) __hip_bfloat16 hv[8];
#pragma unroll
        for (int k = 0; k < 8; ++k)
            hv[k] = __float2bfloat16(tile[xq][j * 8 + k]);
        *(uint4*)((char*)r0 + (size_t)p * 128 + ((j ^ (p & 7)) << 4)) =
            *(const uint4*)hv;
    }
}

// ---------------- conv stage: barrier-free within each source ---------------
// Block: image b = blk>>1, strip y0 = (blk&1)*16. Wave wv: rows y0+2wv,+1.
// A-frag: l15 = px, quad*8+q*32 = in-ch. B-frag: l15 = storage col (true oc
// = l15*4+n). C/D: M(pixel) = quad*4+r.
template <int NSRC, bool FINAL>
__global__ __launch_bounds__(512, 1) void conv_stage(
    const __hip_bfloat16* __restrict__ s0,
    const __hip_bfloat16* __restrict__ s1,
    const __hip_bfloat16* __restrict__ s2,
    const __hip_bfloat16* __restrict__ wt,
    void* __restrict__ dstv, int l0) {
    extern __shared__ char smem[];               // A_LDS + B_LDS = 152064 B
    char* smemB = smem + A_LDS;
    int tid = threadIdx.x;
    int wv = tid >> 6, lane = tid & 63;
    int quad = lane >> 4, l15 = lane & 15;
    int blk = blockIdx.x;
    int b = blk >> 1, y0 = (blk & 1) << 4;

    const char* srcs[3] = {(const char*)s0, (const char*)s1, (const char*)s2};
    const char* gW = (const char*)wt + (size_t)l0 * 9 * (size_t)TAPB;
    const size_t aOff = (size_t)(b * PADW + y0) * PADW * 128;

    auto stage_A = [&](int s) {      // initial: 18 rows, linear 16B DMA copy
        const char* gA = srcs[s] + aOff;
#pragma unroll
        for (int it = 0; it < 10; ++it) {
            int c = it * 512 + tid;
            if (it < 9 || tid < A_TAIL)
                gld16(gA + (size_t)c * 16, smem + (it * 512 + wv * 64) * 16);
        }
    };
    auto stage_B = [&](int s) {      // 9 taps of src s, linear 16B DMA copy
        const char* gB = gW + (size_t)s * 9 * TAPB;
#pragma unroll
        for (int it = 0; it < 9; ++it) {
            int c = it * 512 + tid;
            gld16(gB + (size_t)c * 16, smemB + (it * 512 + wv * 64) * 16);
        }
    };

    floatx4 acc[4][4];
#pragma unroll
    for (int m = 0; m < 4; ++m)
#pragma unroll
        for (int n = 0; n < 4; ++n) acc[m][n] = (floatx4){0.f, 0.f, 0.f, 0.f};

    stage_A(0);
    stage_B(0);
    __syncthreads();                 // src0 operands resident

    uint4 pfA[10];                   // A-only next-source prefetch (40 VGPRs)

#pragma unroll 1
    for (int s = 0; s < NSRC; ++s) {
        if (s + 1 < NSRC) {          // issue next-A loads; complete under MFMA
            const char* gA = srcs[s + 1] + aOff;
#pragma unroll
            for (int it = 0; it < 10; ++it)   // unconditional: stray reads
                pfA[it] = *(const uint4*)(gA + (size_t)(it * 512 + tid) * 16);
            __builtin_amdgcn_sched_barrier(0);  // pin issue point
        }
#pragma unroll
        for (int tl = 0; tl < 9; ++tl) {
            const int ky = tl / 3, kx = tl % 3;
#pragma unroll
            for (int q = 0; q < 2; ++q) {
                bf16x8 Af[4], Bf[4];
#pragma unroll
                for (int m = 0; m < 4; ++m) {
                    int arow = 2 * wv + (m >> 1) + ky;      // LDS row 0..17
                    int apx  = ((m & 1) << 4) + l15 + kx;   // 0..33
                    int R = b * PADW + y0 + arow;           // global pad row
                    int slot = ((q << 2) + quad) ^ ((2 * R + apx) & 7);
                    Af[m] = *(const bf16x8*)(smem + arow * ROWB +
                                             apx * 128 + slot * 16);
                }
#pragma unroll
                for (int n = 0; n < 4; ++n) {
                    int o = (n << 4) + l15;                 // storage col
                    int slot = ((q << 2) + quad) ^ (l15 & 7);
                    Bf[n] = *(const bf16x8*)(smemB + tl * TAPB +
                                             o * 128 + slot * 16);
                }
                __builtin_amdgcn_s_setprio(1);
#pragma unroll
                for (int m = 0; m < 4; ++m)
#pragma unroll
                    for (int n = 0; n < 4; ++n)
                        acc[m][n] = __builtin_amdgcn_mfma_f32_16x16x32_bf16(
                            Af[m], Bf[n], acc[m][n], 0, 0, 0);
                __builtin_amdgcn_s_setprio(0);
            }
        }
        if (s + 1 < NSRC) {          // source switch
            __syncthreads();         // all waves done reading src s operands
#pragma unroll
            for (int it = 0; it < 10; ++it)     // commit A (store MUST be
                if (it < 9 || tid < A_TAIL)     //  bounded: row18+ = smemB!)
                    *(uint4*)(smem + (size_t)(it * 512 + tid) * 16) = pfA[it];
            stage_B(s + 1);          // B from L2-hot wt (~0.5us)
            __syncthreads();         // lgkm + vmcnt drained by barrier
        }
    }

    // Epilogue. M(pixel)=quad*4+r (+16 odd m-tile); acc col c=n*16+l15 holds
    // TRUE oc l15*4+n (wt oc-permuted) -> lane's 4 n-values are contiguous.
    if (FINAL) {
        float* out = (float*)dstv;   // fp32 NCHW [128][64][32][32]
#pragma unroll
        for (int m = 0; m < 4; ++m) {
            int row = y0 + 2 * wv + (m >> 1);
#pragma unroll
            for (int n = 0; n < 4; ++n) {
                int o = (l15 << 2) + n;                     // TRUE oc
                *(floatx4*)(out + (((size_t)b * 64 + o) * 32 + row) * 32 +
                            ((m & 1) << 4) + (quad << 2)) = acc[m][n];
            }
        }
    } else {
        __hip_bfloat16* out = (__hip_bfloat16*)dstv;  // relu -> swizzled NHWC
#pragma unroll
        for (int m = 0; m < 4; ++m) {
            int row = y0 + 2 * wv + (m >> 1);
#pragma unroll
            for (int r = 0; r < 4; ++r) {
                int x = ((m & 1) << 4) + (quad << 2) + r;
                int p = (b * PADW + row + 1) * PADW + x + 1;
                alignas(8) __hip_bfloat16 hv[4];
#pragma unroll
                for (int n = 0; n < 4; ++n)
                    hv[n] = __float2bfloat16(fmaxf(acc[m][n][r], 0.f));
                // true chs l15*4..+3 = storage chunk l15>>1, half (l15&1)
                char* d8 = (char*)out + (size_t)p * 128 +
                           ((((l15 >> 1) ^ (p & 7)) << 4) + ((l15 & 1) << 3));
                *(uint2*)d8 = *(const uint2*)hv;
            }
        }
    }
}

// ---------------------------------------------------------------------------
extern "C" void kernel_launch(void* const* d_in, const int* in_sizes, int n_in,
                              void* d_out, int out_size, void* d_ws,
                              size_t ws_size, hipStream_t stream) {
    const float* inputs  = (const float*)d_in[0];
    const float* alphas1 = (const float*)d_in[1];
    const float* alphas2 = (const float*)d_in[2];
    const float* W       = (const float*)d_in[3];
    char* ws = (char*)d_ws;

    __hip_bfloat16* wt = (__hip_bfloat16*)(ws);                     // 442 KB
    __hip_bfloat16* r0 = (__hip_bfloat16*)(ws + ((size_t)1 << 20)); // 18.9 MB
    __hip_bfloat16* r1 = (__hip_bfloat16*)(ws + ((size_t)20 << 20));
    __hip_bfloat16* r2 = (__hip_bfloat16*)(ws + ((size_t)40 << 20));
    float* out = (float*)d_out;

    // Opt-in to >64KB dynamic LDS (idempotent; harmless under graph capture).
    (void)hipFuncSetAttribute((const void*)conv_stage<1, false>,
                              hipFuncAttributeMaxDynamicSharedMemorySize,
                              SMEM_BYTES);
    (void)hipFuncSetAttribute((const void*)conv_stage<2, false>,
                              hipFuncAttributeMaxDynamicSharedMemorySize,
                              SMEM_BYTES);
    (void)hipFuncSetAttribute((const void*)conv_stage<3, true>,
                              hipFuncAttributeMaxDynamicSharedMemorySize,
                              SMEM_BYTES);

    pre_kernel<<<864 + 128 + 4096, 256, 0, stream>>>(inputs, alphas1, alphas2,
                                                     W, wt, r0, r1, r2);
    conv_stage<1, false><<<256, 512, SMEM_BYTES, stream>>>(r0, r1, r2, wt,
                                                           (void*)r1, 0);
    conv_stage<2, false><<<256, 512, SMEM_BYTES, stream>>>(r0, r1, r2, wt,
                                                           (void*)r2, 1);
    conv_stage<3, true ><<<256, 512, SMEM_BYTES, stream>>>(r0, r1, r2, wt,
                                                           (void*)out, 3);
}

// Round 6
// 148.940 us; speedup vs baseline: 1.6208x; 1.1407x over previous
//
#include <hip/hip_runtime.h>
#include <hip/hip_bf16.h>

// ---------------------------------------------------------------------------
// InferCellV2 R12: champion structure + explicit 1-deep fragment pipeline.
// R7/R10/R11 tri-fail: register prefetch across __syncthreads + unrolled MFMA
// region ALWAYS spills (compiler refuses the live-range) -> dropped for good.
// R11 counters: MfmaUtil 22.4%, VALUBusy 8.7% - both pipes idle. Two rival
// models: (P) LDS pipe at ~12cyc/b128 -> 64 reads/step = 768cyc vs 160cyc
// MFMA/SIMD -> 21% ceiling (matches measurement); (L) latency-bound because
// the compiler never hoists step i+1's ds_reads over step i's MFMAs (1-deep
// pipeline missing). R12 is the discriminating experiment: explicit register
// double-buffer fA/fB[2][4] (static indices only, rule #20), load step i+1
// while MFMA-ing step i. If L: MfmaUtil 35-50%, total ~110us. If P: pinned
// 22% -> structure is at its LDS-pipe roofline, pivot to cutting LDS bytes.
// Kept from R11 (verified passing): oc-permuted wt (acc col n*16+l15 = true
// oc l15*4+n -> 8B-contiguous bf16 node epilogue), __launch_bounds__(512,1).
// Layouts (verified conflict-free R3/R6):
//   activations: zero-padded NHWC bf16 [B][34][34][64], chunk cb of pixel p
//     at p*128 + ((cb^(p&7))*16); weights wt[l][tap][o_s][i], chunk i>>3 of
//     row o_s at slot (i>>3)^(o_s&7). Staging = linear 16B gld_lds chunks.
// Block 512 thr / 8 waves / 16 out rows; grid 256 = 1 block/CU.
// Wave tile 64px x 64oc = 4x4 MFMA 16x16x32, 64 acc + 64 frag VGPRs.
// ---------------------------------------------------------------------------

typedef __bf16 bf16x8 __attribute__((ext_vector_type(8)));
typedef float floatx4 __attribute__((ext_vector_type(4)));
typedef unsigned int uint32;

#define PADW 34
#define PIMG (PADW * PADW)
#define ROWB (PADW * 64 * 2)        // 4352 B per padded NHWC row
#define A_LDS (18 * ROWB)           // 78336 (16 out rows + 2 halo)
#define A_CHUNKS (A_LDS / 16)       // 4896 = 9*512 + 288
#define A_TAIL (A_CHUNKS - 9 * 512) // 288
#define TAPB (64 * 64 * 2)          // 8192 B per weight tap
#define B_LDS (9 * TAPB)            // 73728
#define SMEM_BYTES (A_LDS + B_LDS)  // 152064 -> 1 block/CU

__device__ __forceinline__ void gld16(const char* g, char* l) {
    __builtin_amdgcn_global_load_lds(
        (const __attribute__((address_space(1))) uint32*)g,
        (__attribute__((address_space(3))) uint32*)l, 16, 0, 0);
}

// ---------------- fused pre-pass: prep_weights + zero_halo + relu_pad -------
__global__ __launch_bounds__(256) void pre_kernel(
    const float* __restrict__ in, const float* __restrict__ a1,
    const float* __restrict__ a2, const float* __restrict__ W,
    __hip_bfloat16* __restrict__ wt, __hip_bfloat16* __restrict__ r0,
    __hip_bfloat16* __restrict__ r1, __hip_bfloat16* __restrict__ r2) {
    __shared__ float tile[32][65];
    int blk = blockIdx.x;
    int tid = threadIdx.x;

    if (blk < 864) {                 // ---- weights: fold scale + swizzle
        int idx = blk * 256 + tid;   // 6*9*64*64 = 221184 exact
        int i = idx & 63;
        int o = (idx >> 6) & 63;     // TRUE oc
        int rest = idx >> 12;
        int t = rest % 9;
        int l = rest / 9;
        int ji = i >> 3, jo = o >> 3;
        float ain = 0.f, aout = 0.f;
#pragma unroll
        for (int j = 0; j < 8; ++j) {
            ain  += (j >= ji) ? a1[j] : 0.f;
            aout += (j >= jo) ? a2[j] : 0.f;
        }
        float v = W[(size_t)((l * 64 + o) * 64 + i) * 9 + t] * ain * aout;
        // storage col o_s: acc col c = n*16+l15 then holds true oc l15*4+n
        int os = ((o & 3) << 4) + (o >> 2);
        size_t e = (size_t)(l * 9 + t) * 4096 + os * 64 +
                   ((((i >> 3) ^ (os & 7)) << 3) + (i & 7));
        wt[e] = __float2bfloat16(v);
    } else if (blk < 992) {          // ---- zero halo ring, image b
        int b = blk - 864;
        __hip_bfloat16* bufs[3] = {r0, r1, r2};
#pragma unroll
        for (int f = 0; f < 3; ++f) {
            uint32* buf = (uint32*)(bufs[f] + (size_t)b * PIMG * 64);
            for (int idx = tid; idx < 132 * 32; idx += 256) {
                int slot = idx >> 5, u = idx & 31;
                int yy, xx;
                if (slot < 34)      { yy = 0;  xx = slot; }
                else if (slot < 68) { yy = 33; xx = slot - 34; }
                else { int s2 = slot - 68; yy = 1 + (s2 >> 1); xx = (s2 & 1) * 33; }
                buf[(size_t)(yy * PADW + xx) * 32 + u] = 0u;
            }
        }
    } else {                         // ---- relu(x) -> padded swizzled NHWC
        int rb = blk - 992;
        int b = rb >> 5, y = rb & 31;
        int x = tid & 31, c0 = tid >> 5;
        const float* ip = in + ((size_t)b * 64 * 32 + y) * 32 + x;
#pragma unroll
        for (int cc = 0; cc < 8; ++cc) {
            int c = cc * 8 + c0;
            tile[x][c] = fmaxf(ip[(size_t)c * 1024], 0.f);
        }
        __syncthreads();
        // one 16B chunk store per thread: thread = (pixel xq, chunk j);
        // chunk j of pixel p lives at p*128 + (j^(p&7))*16.
        int j = tid & 7, xq = tid >> 3;
        int p = (b * PADW + y + 1) * PADW + 1 + xq;
        alignas(16) __hip_bfloat16 hv[8];
#pragma unroll
        for (int k = 0; k < 8; ++k)
            hv[k] = __float2bfloat16(tile[xq][j * 8 + k]);
        *(uint4*)((char*)r0 + (size_t)p * 128 + ((j ^ (p & 7)) << 4)) =
            *(const uint4*)hv;
    }
}

// ---------------- conv stage: pipelined free-run within each source ---------
// Block: image b = blk>>1, strip y0 = (blk&1)*16. Wave wv: rows y0+2wv,+1.
// A-frag: l15 = px, quad*8+q*32 = in-ch. B-frag: l15 = storage col (true oc
// = l15*4+n). C/D: M(pixel) = quad*4+r.
template <int NSRC, bool FINAL>
__global__ __launch_bounds__(512, 1) void conv_stage(
    const __hip_bfloat16* __restrict__ s0,
    const __hip_bfloat16* __restrict__ s1,
    const __hip_bfloat16* __restrict__ s2,
    const __hip_bfloat16* __restrict__ wt,
    void* __restrict__ dstv, int l0) {
    extern __shared__ char smem[];               // A_LDS + B_LDS = 152064 B
    char* smemB = smem + A_LDS;
    int tid = threadIdx.x;
    int wv = tid >> 6, lane = tid & 63;
    int quad = lane >> 4, l15 = lane & 15;
    int blk = blockIdx.x;
    int b = blk >> 1, y0 = (blk & 1) << 4;

    const char* srcs[3] = {(const char*)s0, (const char*)s1, (const char*)s2};
    const char* gW = (const char*)wt + (size_t)l0 * 9 * (size_t)TAPB;
    const size_t aOff = (size_t)(b * PADW + y0) * PADW * 128;

    auto stage_A = [&](int s) {      // 18 padded rows, linear 16B DMA copy
        const char* gA = srcs[s] + aOff;
#pragma unroll
        for (int it = 0; it < 10; ++it) {
            int c = it * 512 + tid;
            if (it < 9 || tid < A_TAIL)
                gld16(gA + (size_t)c * 16, smem + (it * 512 + wv * 64) * 16);
        }
    };
    auto stage_B = [&](int s) {      // 9 taps of src s, linear 16B DMA copy
        const char* gB = gW + (size_t)s * 9 * TAPB;
#pragma unroll
        for (int it = 0; it < 9; ++it) {
            int c = it * 512 + tid;
            gld16(gB + (size_t)c * 16, smemB + (it * 512 + wv * 64) * 16);
        }
    };

    // fragment loaders (step = (tap, q)); all indices compile-time when
    // called from the fully-unrolled pipeline loop.
    auto ldA = [&](int tl, int q, bf16x8 (&dst)[4]) {
        const int ky = tl / 3, kx = tl % 3;
#pragma unroll
        for (int m = 0; m < 4; ++m) {
            int arow = 2 * wv + (m >> 1) + ky;      // LDS row 0..17
            int apx  = ((m & 1) << 4) + l15 + kx;   // 0..33
            int R = b * PADW + y0 + arow;           // global padded row
            int slot = ((q << 2) + quad) ^ ((2 * R + apx) & 7);
            dst[m] = *(const bf16x8*)(smem + arow * ROWB + apx * 128 +
                                      slot * 16);
        }
    };
    auto ldB = [&](int tl, int q, bf16x8 (&dst)[4]) {
#pragma unroll
        for (int n = 0; n < 4; ++n) {
            int o = (n << 4) + l15;                 // storage col
            int slot = ((q << 2) + quad) ^ (l15 & 7);
            dst[n] = *(const bf16x8*)(smemB + tl * TAPB + o * 128 +
                                      slot * 16);
        }
    };

    floatx4 acc[4][4];
#pragma unroll
    for (int m = 0; m < 4; ++m)
#pragma unroll
        for (int n = 0; n < 4; ++n) acc[m][n] = (floatx4){0.f, 0.f, 0.f, 0.f};

    stage_A(0);
    stage_B(0);
    __syncthreads();                 // src0 operands resident

#pragma unroll 1
    for (int s = 0; s < NSRC; ++s) {
        // ---- 18-step (tap x q) loop, 1-deep register pipeline ----
        bf16x8 fA[2][4], fB[2][4];
        ldA(0, 0, fA[0]);
        ldB(0, 0, fB[0]);
#pragma unroll
        for (int st = 0; st < 18; ++st) {
            const int pb = st & 1;               // compile-time under unroll
            if (st < 17) {                       // load step st+1 into pb^1
                const int nt = (st + 1) >> 1, nq = (st + 1) & 1;
                ldA(nt, nq, fA[pb ^ 1]);
                ldB(nt, nq, fB[pb ^ 1]);
            }
            __builtin_amdgcn_s_setprio(1);
#pragma unroll
            for (int m = 0; m < 4; ++m)
#pragma unroll
                for (int n = 0; n < 4; ++n)
                    acc[m][n] = __builtin_amdgcn_mfma_f32_16x16x32_bf16(
                        fA[pb][m], fB[pb][n], acc[m][n], 0, 0, 0);
            __builtin_amdgcn_s_setprio(0);
        }
        if (s + 1 < NSRC) {          // source switch (R6 semantics)
            __syncthreads();         // all waves done reading src s operands
            stage_A(s + 1);
            stage_B(s + 1);
            __syncthreads();         // staging drained (vmcnt0 via barrier)
        }
    }

    // Epilogue. M(pixel)=quad*4+r (+16 odd m-tile); acc col c=n*16+l15 holds
    // TRUE oc l15*4+n (wt oc-permuted) -> lane's 4 n-values are contiguous.
    if (FINAL) {
        float* out = (float*)dstv;   // fp32 NCHW [128][64][32][32]
#pragma unroll
        for (int m = 0; m < 4; ++m) {
            int row = y0 + 2 * wv + (m >> 1);
#pragma unroll
            for (int n = 0; n < 4; ++n) {
                int o = (l15 << 2) + n;                     // TRUE oc
                *(floatx4*)(out + (((size_t)b * 64 + o) * 32 + row) * 32 +
                            ((m & 1) << 4) + (quad << 2)) = acc[m][n];
            }
        }
    } else {
        __hip_bfloat16* out = (__hip_bfloat16*)dstv;  // relu -> swizzled NHWC
#pragma unroll
        for (int m = 0; m < 4; ++m) {
            int row = y0 + 2 * wv + (m >> 1);
#pragma unroll
            for (int r = 0; r < 4; ++r) {
                int x = ((m & 1) << 4) + (quad << 2) + r;
                int p = (b * PADW + row + 1) * PADW + x + 1;
                alignas(8) __hip_bfloat16 hv[4];
#pragma unroll
                for (int n = 0; n < 4; ++n)
                    hv[n] = __float2bfloat16(fmaxf(acc[m][n][r], 0.f));
                // true chs l15*4..+3 = storage chunk l15>>1, half (l15&1)
                char* d8 = (char*)out + (size_t)p * 128 +
                           ((((l15 >> 1) ^ (p & 7)) << 4) + ((l15 & 1) << 3));
                *(uint2*)d8 = *(const uint2*)hv;
            }
        }
    }
}

// ---------------------------------------------------------------------------
extern "C" void kernel_launch(void* const* d_in, const int* in_sizes, int n_in,
                              void* d_out, int out_size, void* d_ws,
                              size_t ws_size, hipStream_t stream) {
    const float* inputs  = (const float*)d_in[0];
    const float* alphas1 = (const float*)d_in[1];
    const float* alphas2 = (const float*)d_in[2];
    const float* W       = (const float*)d_in[3];
    char* ws = (char*)d_ws;

    __hip_bfloat16* wt = (__hip_bfloat16*)(ws);                     // 442 KB
    __hip_bfloat16* r0 = (__hip_bfloat16*)(ws + ((size_t)1 << 20)); // 18.9 MB
    __hip_bfloat16* r1 = (__hip_bfloat16*)(ws + ((size_t)20 << 20));
    __hip_bfloat16* r2 = (__hip_bfloat16*)(ws + ((size_t)40 << 20));
    float* out = (float*)d_out;

    // Opt-in to >64KB dynamic LDS (idempotent; harmless under graph capture).
    (void)hipFuncSetAttribute((const void*)conv_stage<1, false>,
                              hipFuncAttributeMaxDynamicSharedMemorySize,
                              SMEM_BYTES);
    (void)hipFuncSetAttribute((const void*)conv_stage<2, false>,
                              hipFuncAttributeMaxDynamicSharedMemorySize,
                              SMEM_BYTES);
    (void)hipFuncSetAttribute((const void*)conv_stage<3, true>,
                              hipFuncAttributeMaxDynamicSharedMemorySize,
                              SMEM_BYTES);

    pre_kernel<<<864 + 128 + 4096, 256, 0, stream>>>(inputs, alphas1, alphas2,
                                                     W, wt, r0, r1, r2);
    conv_stage<1, false><<<256, 512, SMEM_BYTES, stream>>>(r0, r1, r2, wt,
                                                           (void*)r1, 0);
    conv_stage<2, false><<<256, 512, SMEM_BYTES, stream>>>(r0, r1, r2, wt,
                                                           (void*)r2, 1);
    conv_stage<3, true ><<<256, 512, SMEM_BYTES, stream>>>(r0, r1, r2, wt,
                                                           (void*)out, 3);
}